// Round 3
// baseline (468.786 us; speedup 1.0000x reference)
//
#include <hip/hip_runtime.h>
#include <hip/hip_bf16.h>

// B=1, H=4, T=1024, D=8192. fp32 in/out (per reference setup_inputs dtype).
// O[h,t,d] = sum_{s<t} (ropeQ[h,t,:]·ropeQ[h,s,:]/sqrt(D)) * V[h,s,d]
// ws (88MB): Qr(bf16) 64MB | S32(f32) 16MB | Sbf(bf16) 8MB

typedef __bf16 bf16x8 __attribute__((ext_vector_type(8)));
typedef __bf16 bf16x2 __attribute__((ext_vector_type(2)));
typedef float  f32x4  __attribute__((ext_vector_type(4)));

#define HEAD_STRIDE (1024ull * 8192ull)   // elements per head, = 1<<23

__device__ inline void gl_lds16(const void* g, void* l) {
  __builtin_amdgcn_global_load_lds(
      (__attribute__((address_space(1))) void*)(g),
      (__attribute__((address_space(3))) void*)(l), 16, 0, 0);
}

// ---------------- RoPE (head-slicing reshape quirk), f32 -> bf16 ----------------
// v_rot[h,t,d] = (d even ? -Q[hh+1, st, sd] : +Q[hh, st, sd])
//   hh = h&~1, st = 512*(h&1) + (t>>1), sd = (d>>1) + 4096*(t&1)
__global__ __launch_bounds__(256) void rope_kernel(const float* __restrict__ Q,
                                                   __bf16* __restrict__ Qr) {
  int gid = blockIdx.x * 256 + threadIdx.x;          // 4,194,304 threads x 8 elems
  size_t e8 = (size_t)gid * 8;
  int d0 = (int)(e8 & 8191);
  int t  = (int)((e8 >> 13) & 1023);
  int h  = (int)(e8 >> 23);

  f32x4 qa = *(const f32x4*)(Q + e8);
  f32x4 qb = *(const f32x4*)(Q + e8 + 4);
  int pt   = t & 1;
  int srct = ((h & 1) << 9) + (t >> 1);
  int sd   = (d0 >> 1) + (pt << 12);
  int hh   = h & ~1;
  size_t soff = ((size_t)srct << 13) + (size_t)sd;
  f32x4 a4 = *(const f32x4*)(Q + (size_t)(hh + 1) * HEAD_STRIDE + soff); // even d, sign -
  f32x4 b4 = *(const f32x4*)(Q + (size_t)hh       * HEAD_STRIDE + soff); // odd d,  sign +

  float qv[8];
#pragma unroll
  for (int i = 0; i < 4; ++i) { qv[i] = qa[i]; qv[4 + i] = qb[i]; }

  bf16x8 o;
  float tf = (float)t;
#pragma unroll
  for (int p = 0; p < 4; ++p) {
    float qd = (float)(d0 + 2 * p);
    float fr = exp2f(-qd * (1.0f / 512.0f)) * 0.15915494309189535f; // theta=2^16, /2pi
    float x = tf * fr;
    x -= floorf(x);
    float sn, cs;
    __sincosf(x * 6.283185307179586f, &sn, &cs);
    o[2 * p]     = (__bf16)(qv[2 * p]     * cs - a4[p] * sn);
    o[2 * p + 1] = (__bf16)(qv[2 * p + 1] * cs + b4[p] * sn);
  }
  *(bf16x8*)(Qr + e8) = o;
}

// ---------------- Stage 1: S32[t,s] += scale * Qr[t,:]·Qr[s,:], strictly causal ----------------
// grid = 4 heads * 36 lower-tri 128-tiles * splitK(4) = 576 blocks
__global__ __launch_bounds__(256) void s1_qqt(const __bf16* __restrict__ Qr,
                                              float* __restrict__ S32) {
  __shared__ __align__(16) __bf16 As[128 * 64];
  __shared__ __align__(16) __bf16 Bs[128 * 64];
  int bid = blockIdx.x;
  int split = bid & 3; bid >>= 2;
  int pair = bid % 36, h = bid / 36;
  int ti = 0, p = pair;
  while (p > ti) { p -= ti + 1; ++ti; }
  int si = p;                                       // si <= ti

  const __bf16* Abase = Qr + (size_t)h * HEAD_STRIDE + ((size_t)(ti * 128) << 13) + split * 2048;
  const __bf16* Bbase = Qr + (size_t)h * HEAD_STRIDE + ((size_t)(si * 128) << 13) + split * 2048;

  int tid = threadIdx.x, lane = tid & 63, wave = tid >> 6;
  int wm = (wave & 1) << 6, wn = (wave >> 1) << 6;
  int l16 = lane & 15, q4 = lane >> 4;
  int srow = lane >> 3, scol = (lane & 7) * 8;

  f32x4 acc[4][4] = {};

  for (int kk = 0; kk < 2048; kk += 64) {
#pragma unroll
    for (int j = 0; j < 4; ++j) {
      int c = wave * 4 + j;
      int row = c * 8 + srow;
      gl_lds16(Abase + (size_t)row * 8192 + kk + scol, &As[c * 512]);
      gl_lds16(Bbase + (size_t)row * 8192 + kk + scol, &Bs[c * 512]);
    }
    __syncthreads();
#pragma unroll
    for (int ks = 0; ks < 64; ks += 32) {
      bf16x8 af[4], bfr[4];
#pragma unroll
      for (int i = 0; i < 4; ++i)
        af[i] = *(const bf16x8*)&As[(wm + i * 16 + l16) * 64 + ks + q4 * 8];
#pragma unroll
      for (int i = 0; i < 4; ++i)
        bfr[i] = *(const bf16x8*)&Bs[(wn + i * 16 + l16) * 64 + ks + q4 * 8];
#pragma unroll
      for (int i = 0; i < 4; ++i)
#pragma unroll
        for (int j = 0; j < 4; ++j)
          acc[i][j] = __builtin_amdgcn_mfma_f32_16x16x32_bf16(af[i], bfr[j], acc[i][j], 0, 0, 0);
    }
    __syncthreads();
  }

  const float scale = 0.011048543456039806f;        // 1/sqrt(8192)
  int t_base = ti * 128 + wm, s_base = si * 128 + wn;
  float* Sh = S32 + ((size_t)h << 20);
#pragma unroll
  for (int i = 0; i < 4; ++i)
#pragma unroll
    for (int j = 0; j < 4; ++j) {
      int col = s_base + j * 16 + l16;              // s
#pragma unroll
      for (int r = 0; r < 4; ++r) {
        int row = t_base + i * 16 + q4 * 4 + r;     // t
        if (col < row)                               // strict causal; skipped -> stays 0
          atomicAdd(&Sh[((size_t)row << 10) + col], acc[i][j][r] * scale);
      }
    }
}

// ---------------- S32 -> bf16 ----------------
__global__ __launch_bounds__(256) void cvt_kernel(const float* __restrict__ S32,
                                                  __bf16* __restrict__ Sbf) {
  int gid = blockIdx.x * 256 + threadIdx.x;         // 524288 threads
  size_t e = (size_t)gid * 8;
  f32x4 a = *(const f32x4*)(S32 + e);
  f32x4 b = *(const f32x4*)(S32 + e + 4);
  bf16x8 o;
#pragma unroll
  for (int i = 0; i < 4; ++i) { o[i] = (__bf16)a[i]; o[4 + i] = (__bf16)b[i]; }
  *(bf16x8*)(Sbf + e) = o;
}

// ---------------- Stage 3: O[t,d] = sum_s S[t,s] * V[s,d], K truncated by causality ----------------
// A = Sbf (bf16, K=s contiguous, global_load_lds). B = V (f32) converted+transposed into
// XOR-swizzled LDS: element (d-row r, s-col c) lives at r*64 + ((c>>3)^(r&7))*8 + (c&7).
// grid = 4 heads * 8 t-tiles * 64 d-tiles = 2048 blocks
__global__ __launch_bounds__(256) void s3_sv(const __bf16* __restrict__ Sbf,
                                             const float* __restrict__ V,
                                             float* __restrict__ out) {
  __shared__ __align__(16) __bf16 As[128 * 64];     // [t'][s'] stride 64
  __shared__ __align__(16) __bf16 Bs[128 * 64];     // [d'][s'] swizzled
  int bid = blockIdx.x;
  int dt = bid & 63; bid >>= 6;
  int tt = 7 - (bid & 7);                           // long-K blocks dispatched first
  int h = bid >> 3;

  const __bf16* Abase = Sbf + ((size_t)h << 20) + ((size_t)(tt * 128) << 10);
  const float* Vh = V + (size_t)h * HEAD_STRIDE;
  int dbase = dt * 128;
  int Kmax = tt * 128 + 128;

  int tid = threadIdx.x, lane = tid & 63, wave = tid >> 6;
  int wm = (wave & 1) << 6, wn = (wave >> 1) << 6;
  int l16 = lane & 15, q4 = lane >> 4;
  int srow = lane >> 3, scol = (lane & 7) * 8;
  int q  = tid & 31;                                // d-lane
  int pp = tid >> 5;                                // 0..7 s-pair group

  f32x4 acc[4][4] = {};

  for (int kk = 0; kk < Kmax; kk += 64) {
    // A tile via global_load_lds (m97 pattern)
#pragma unroll
    for (int j = 0; j < 4; ++j) {
      int c = wave * 4 + j;
      int row = c * 8 + srow;
      gl_lds16(Abase + (size_t)row * 1024 + kk + scol, &As[c * 512]);
    }
    // B tile: V[kk+s'][dbase+r] (f32) -> bf16 -> Bs swizzled, transposed.
    // Each thread: d-rows r = q+32j, s-pairs s0 = pass*16 + pp*2.
#pragma unroll
    for (int pass = 0; pass < 4; ++pass) {
      int s0 = pass * 16 + pp * 2;
      const float* v0p = Vh + (size_t)(kk + s0) * 8192 + dbase;
      const float* v1p = v0p + 8192;
#pragma unroll
      for (int j = 0; j < 4; ++j) {
        int r = q + 32 * j;
        float v0 = v0p[r], v1 = v1p[r];
        int e = r * 64 + (((s0 >> 3) ^ (r & 7)) << 3) + (s0 & 7);
        *(bf16x2*)&Bs[e] = bf16x2{(__bf16)v0, (__bf16)v1};
      }
    }
    __syncthreads();
#pragma unroll
    for (int ks = 0; ks < 64; ks += 32) {
      bf16x8 af[4], bfr[4];
#pragma unroll
      for (int i = 0; i < 4; ++i)
        af[i] = *(const bf16x8*)&As[(wm + i * 16 + l16) * 64 + ks + q4 * 8];
#pragma unroll
      for (int i = 0; i < 4; ++i) {
        int r = wn + i * 16 + l16;
        int oct = ((ks >> 3) + q4) ^ (r & 7);
        bfr[i] = *(const bf16x8*)&Bs[r * 64 + oct * 8];
      }
#pragma unroll
      for (int i = 0; i < 4; ++i)
#pragma unroll
        for (int j = 0; j < 4; ++j)
          acc[i][j] = __builtin_amdgcn_mfma_f32_16x16x32_bf16(af[i], bfr[j], acc[i][j], 0, 0, 0);
    }
    __syncthreads();
  }

  int t_base = tt * 128 + wm, d_base = dbase + wn;
  float* obase = out + (size_t)h * HEAD_STRIDE;
#pragma unroll
  for (int i = 0; i < 4; ++i)
#pragma unroll
    for (int j = 0; j < 4; ++j) {
      int col = d_base + j * 16 + l16;              // d
#pragma unroll
      for (int r = 0; r < 4; ++r) {
        int row = t_base + i * 16 + q4 * 4 + r;     // t
        obase[((size_t)row << 13) + col] = acc[i][j][r];
      }
    }
}

extern "C" void kernel_launch(void* const* d_in, const int* in_sizes, int n_in,
                              void* d_out, int out_size, void* d_ws, size_t ws_size,
                              hipStream_t stream) {
  const float* query = (const float*)d_in[0];
  const float* value = (const float*)d_in[1];
  float* out = (float*)d_out;

  char* ws = (char*)d_ws;
  __bf16* Qr  = (__bf16*)ws;                        // 67108864 B
  float*  S32 = (float*) (ws + 67108864);           // 16777216 B
  __bf16* Sbf = (__bf16*)(ws + 83886080);           //  8388608 B  (total 88 MB)

  hipMemsetAsync(S32, 0, 16777216, stream);
  rope_kernel<<<16384, 256, 0, stream>>>(query, Qr);
  s1_qqt<<<576, 256, 0, stream>>>(Qr, S32);
  cvt_kernel<<<2048, 256, 0, stream>>>(S32, Sbf);
  s3_sv<<<2048, 256, 0, stream>>>(Sbf, value, out);
}

// Round 4
// 460.250 us; speedup vs baseline: 1.0185x; 1.0185x over previous
//
#include <hip/hip_runtime.h>
#include <hip/hip_bf16.h>

// B=1, H=4, T=1024, D=8192. fp32 in/out.
// O[h,t,d] = sum_{s<t} (ropeQ[h,t,:]·ropeQ[h,s,:]/sqrt(D)) * V[h,s,d]
// ws (88MB): Qr(bf16) 64MB [reused as Vt after s1] | S32(f32) 16MB | Sbf(bf16) 8MB

typedef __bf16 bf16x8 __attribute__((ext_vector_type(8)));
typedef float  f32x4  __attribute__((ext_vector_type(4)));

#define HEAD_STRIDE (1024ull * 8192ull)   // elements per head, = 1<<23

__device__ inline void gl_lds16(const void* g, void* l) {
  __builtin_amdgcn_global_load_lds(
      (__attribute__((address_space(1))) void*)(g),
      (__attribute__((address_space(3))) void*)(l), 16, 0, 0);
}

// ---------------- RoPE (head-slicing reshape quirk), f32 -> bf16 ----------------
__global__ __launch_bounds__(256) void rope_kernel(const float* __restrict__ Q,
                                                   __bf16* __restrict__ Qr) {
  int gid = blockIdx.x * 256 + threadIdx.x;          // 4,194,304 threads x 8 elems
  size_t e8 = (size_t)gid * 8;
  int d0 = (int)(e8 & 8191);
  int t  = (int)((e8 >> 13) & 1023);
  int h  = (int)(e8 >> 23);

  f32x4 qa = *(const f32x4*)(Q + e8);
  f32x4 qb = *(const f32x4*)(Q + e8 + 4);
  int pt   = t & 1;
  int srct = ((h & 1) << 9) + (t >> 1);
  int sd   = (d0 >> 1) + (pt << 12);
  int hh   = h & ~1;
  size_t soff = ((size_t)srct << 13) + (size_t)sd;
  f32x4 a4 = *(const f32x4*)(Q + (size_t)(hh + 1) * HEAD_STRIDE + soff); // even d, sign -
  f32x4 b4 = *(const f32x4*)(Q + (size_t)hh       * HEAD_STRIDE + soff); // odd d,  sign +

  float qv[8];
#pragma unroll
  for (int i = 0; i < 4; ++i) { qv[i] = qa[i]; qv[4 + i] = qb[i]; }

  bf16x8 o;
  float tf = (float)t;
#pragma unroll
  for (int p = 0; p < 4; ++p) {
    float qd = (float)(d0 + 2 * p);
    float fr = exp2f(-qd * (1.0f / 512.0f)) * 0.15915494309189535f; // theta=2^16, /2pi
    float x = tf * fr;
    x -= floorf(x);
    float sn, cs;
    __sincosf(x * 6.283185307179586f, &sn, &cs);
    o[2 * p]     = (__bf16)(qv[2 * p]     * cs - a4[p] * sn);
    o[2 * p + 1] = (__bf16)(qv[2 * p + 1] * cs + b4[p] * sn);
  }
  *(bf16x8*)(Qr + e8) = o;
}

// ---------------- Stage 1: S32[t,s] += scale * Qr[t,:]·Qr[s,:], strictly causal ----------------
// grid = 4 heads * 36 lower-tri 128-tiles * splitK(8) = 1152 blocks
// LDS tiles XOR-octet swizzled: LDS slot (row r, octet c) holds global octet c^(r&7).
__global__ __launch_bounds__(256) void s1_qqt(const __bf16* __restrict__ Qr,
                                              float* __restrict__ S32) {
  __shared__ __align__(16) __bf16 As[128 * 64];
  __shared__ __align__(16) __bf16 Bs[128 * 64];
  int bid = blockIdx.x;
  int split = bid & 7; bid >>= 3;
  int pair = bid % 36, h = bid / 36;
  int ti = 0, p = pair;
  while (p > ti) { p -= ti + 1; ++ti; }
  int si = p;                                       // si <= ti

  const __bf16* Abase = Qr + (size_t)h * HEAD_STRIDE + ((size_t)(ti * 128) << 13) + split * 1024;
  const __bf16* Bbase = Qr + (size_t)h * HEAD_STRIDE + ((size_t)(si * 128) << 13) + split * 1024;

  int tid = threadIdx.x, lane = tid & 63, wave = tid >> 6;
  int wm = (wave & 1) << 6, wn = (wave >> 1) << 6;
  int l16 = lane & 15, q4 = lane >> 4;
  int srow = lane >> 3;                             // 0..7
  int scol = ((lane & 7) ^ srow) * 8;               // swizzled source octet

  f32x4 acc[4][4] = {};

  for (int kk = 0; kk < 1024; kk += 64) {
#pragma unroll
    for (int j = 0; j < 4; ++j) {
      int c = wave * 4 + j;
      int row = c * 8 + srow;
      gl_lds16(Abase + (size_t)row * 8192 + kk + scol, &As[c * 512]);
      gl_lds16(Bbase + (size_t)row * 8192 + kk + scol, &Bs[c * 512]);
    }
    __syncthreads();
#pragma unroll
    for (int ks = 0; ks < 64; ks += 32) {
      bf16x8 af[4], bfr[4];
#pragma unroll
      for (int i = 0; i < 4; ++i) {
        int r = wm + i * 16 + l16;
        af[i] = *(const bf16x8*)&As[r * 64 + (((q4 + (ks >> 3)) ^ (r & 7)) << 3)];
      }
#pragma unroll
      for (int i = 0; i < 4; ++i) {
        int r = wn + i * 16 + l16;
        bfr[i] = *(const bf16x8*)&Bs[r * 64 + (((q4 + (ks >> 3)) ^ (r & 7)) << 3)];
      }
#pragma unroll
      for (int i = 0; i < 4; ++i)
#pragma unroll
        for (int j = 0; j < 4; ++j)
          acc[i][j] = __builtin_amdgcn_mfma_f32_16x16x32_bf16(af[i], bfr[j], acc[i][j], 0, 0, 0);
    }
    __syncthreads();
  }

  const float scale = 0.011048543456039806f;        // 1/sqrt(8192)
  int t_base = ti * 128 + wm, s_base = si * 128 + wn;
  float* Sh = S32 + ((size_t)h << 20);
#pragma unroll
  for (int i = 0; i < 4; ++i)
#pragma unroll
    for (int j = 0; j < 4; ++j) {
      int col = s_base + j * 16 + l16;              // s
#pragma unroll
      for (int r = 0; r < 4; ++r) {
        int row = t_base + i * 16 + q4 * 4 + r;     // t
        if (col < row)                               // strict causal; skipped -> stays 0
          atomicAdd(&Sh[((size_t)row << 10) + col], acc[i][j][r] * scale);
      }
    }
}

// ---------------- S32 -> bf16 ----------------
__global__ __launch_bounds__(256) void cvt_kernel(const float* __restrict__ S32,
                                                  __bf16* __restrict__ Sbf) {
  int gid = blockIdx.x * 256 + threadIdx.x;         // 524288 threads
  size_t e = (size_t)gid * 8;
  f32x4 a = *(const f32x4*)(S32 + e);
  f32x4 b = *(const f32x4*)(S32 + e + 4);
  bf16x8 o;
#pragma unroll
  for (int i = 0; i < 4; ++i) { o[i] = (__bf16)a[i]; o[4 + i] = (__bf16)b[i]; }
  *(bf16x8*)(Sbf + e) = o;
}

// ---------------- V transpose+convert: Vt[h][d][s] = bf16(V[h][s][d]) ----------------
// grid = 4 h * 16 s-tiles * 128 d-tiles = 8192 blocks (64x64 tiles)
__global__ __launch_bounds__(256) void transp_kernel(const float* __restrict__ V,
                                                     __bf16* __restrict__ Vt) {
  __shared__ __bf16 L[64 * 72];                     // [d][s], pad 72
  int bid = blockIdx.x;
  int dtile = bid & 127;
  int st = (bid >> 7) & 15;
  int h = bid >> 11;
  int s0 = st << 6, d0 = dtile << 6;
  const float* Vh = V + (size_t)h * HEAD_STRIDE;
  __bf16* Vth = Vt + (size_t)h * HEAD_STRIDE;
  int tid = threadIdx.x;
  int r = tid >> 2;                                 // s-row 0..63
  int c = (tid & 3) << 4;                           // d-col base (16 cols)
#pragma unroll
  for (int j = 0; j < 4; ++j) {
    f32x4 v = *(const f32x4*)(Vh + (size_t)(s0 + r) * 8192 + d0 + c + 4 * j);
#pragma unroll
    for (int e = 0; e < 4; ++e) L[(c + 4 * j + e) * 72 + r] = (__bf16)v[e];
  }
  __syncthreads();
  int row = tid >> 3;                               // d-row 0..31
  int col8 = (tid & 7) << 3;
#pragma unroll
  for (int half = 0; half < 2; ++half) {
    int dr = row + half * 32;
    bf16x8 v = *(const bf16x8*)&L[dr * 72 + col8];
    *(bf16x8*)(Vth + (size_t)(d0 + dr) * 1024 + s0 + col8) = v;
  }
}

// ---------------- Stage 3: O[t,d] = sum_s S[t,s] * Vt[d,s], K truncated by causality ----------------
// grid = 4 heads * 8 t-tiles * 64 d-tiles = 2048 blocks. Pure m97 dual-gl_lds16, swizzled.
__global__ __launch_bounds__(256) void s3_sv(const __bf16* __restrict__ Sbf,
                                             const __bf16* __restrict__ Vt,
                                             float* __restrict__ out) {
  __shared__ __align__(16) __bf16 As[128 * 64];
  __shared__ __align__(16) __bf16 Bs[128 * 64];
  int bid = blockIdx.x;
  int dt = bid & 63; bid >>= 6;
  int tt = 7 - (bid & 7);                           // long-K blocks dispatched first
  int h = bid >> 3;

  const __bf16* Abase = Sbf + ((size_t)h << 20) + ((size_t)(tt * 128) << 10);
  const __bf16* Bbase = Vt + (size_t)h * HEAD_STRIDE + ((size_t)(dt * 128) << 10);
  int Kmax = tt * 128 + 128;

  int tid = threadIdx.x, lane = tid & 63, wave = tid >> 6;
  int wm = (wave & 1) << 6, wn = (wave >> 1) << 6;
  int l16 = lane & 15, q4 = lane >> 4;
  int srow = lane >> 3;
  int scol = ((lane & 7) ^ srow) * 8;               // swizzled source octet

  f32x4 acc[4][4] = {};

  for (int kk = 0; kk < Kmax; kk += 64) {
#pragma unroll
    for (int j = 0; j < 4; ++j) {
      int c = wave * 4 + j;
      int row = c * 8 + srow;
      gl_lds16(Abase + (size_t)row * 1024 + kk + scol, &As[c * 512]);
      gl_lds16(Bbase + (size_t)row * 1024 + kk + scol, &Bs[c * 512]);
    }
    __syncthreads();
#pragma unroll
    for (int ks = 0; ks < 64; ks += 32) {
      bf16x8 af[4], bfr[4];
#pragma unroll
      for (int i = 0; i < 4; ++i) {
        int r = wm + i * 16 + l16;
        af[i] = *(const bf16x8*)&As[r * 64 + (((q4 + (ks >> 3)) ^ (r & 7)) << 3)];
      }
#pragma unroll
      for (int i = 0; i < 4; ++i) {
        int r = wn + i * 16 + l16;
        bfr[i] = *(const bf16x8*)&Bs[r * 64 + (((q4 + (ks >> 3)) ^ (r & 7)) << 3)];
      }
#pragma unroll
      for (int i = 0; i < 4; ++i)
#pragma unroll
        for (int j = 0; j < 4; ++j)
          acc[i][j] = __builtin_amdgcn_mfma_f32_16x16x32_bf16(af[i], bfr[j], acc[i][j], 0, 0, 0);
    }
    __syncthreads();
  }

  int t_base = tt * 128 + wm, d_base = dt * 128 + wn;
  float* obase = out + (size_t)h * HEAD_STRIDE;
#pragma unroll
  for (int i = 0; i < 4; ++i)
#pragma unroll
    for (int j = 0; j < 4; ++j) {
      int col = d_base + j * 16 + l16;              // d
#pragma unroll
      for (int r = 0; r < 4; ++r) {
        int row = t_base + i * 16 + q4 * 4 + r;     // t
        obase[((size_t)row << 13) + col] = acc[i][j][r];
      }
    }
}

extern "C" void kernel_launch(void* const* d_in, const int* in_sizes, int n_in,
                              void* d_out, int out_size, void* d_ws, size_t ws_size,
                              hipStream_t stream) {
  const float* query = (const float*)d_in[0];
  const float* value = (const float*)d_in[1];
  float* out = (float*)d_out;

  char* ws = (char*)d_ws;
  __bf16* Qr  = (__bf16*)ws;                        // 64 MB; dead after s1 -> reused as Vt
  __bf16* Vt  = (__bf16*)ws;                        // aliases Qr (stream-ordered safe)
  float*  S32 = (float*) (ws + 67108864);           // 16 MB
  __bf16* Sbf = (__bf16*)(ws + 83886080);           //  8 MB  (total 88 MB)

  hipMemsetAsync(S32, 0, 16777216, stream);
  rope_kernel<<<16384, 256, 0, stream>>>(query, Qr);
  s1_qqt<<<1152, 256, 0, stream>>>(Qr, S32);
  transp_kernel<<<8192, 256, 0, stream>>>(value, Vt);  // overwrites Qr region (dead)
  cvt_kernel<<<2048, 256, 0, stream>>>(S32, Sbf);
  s3_sv<<<2048, 256, 0, stream>>>(Sbf, Vt, out);
}